// Round 5
// baseline (236.059 us; speedup 1.0000x reference)
//
#include <hip/hip_runtime.h>

// DynamicRouting (capsule routing), MI355X / gfx950.
// votes: [B=128, I=2048, O=32, P=4] fp32 (128 MiB). activations_in unused.
// b_ij^(t)[b,i,o] = sum_{tau<t} dot(votes[b,i,o,:], v^tau[b,o,:]) -> b_ij never materialized.
//
// R10 changes vs R9 (234.5 us = 154 us harness poison-fills + ~80 us ours):
//  R9's kernel B ran ONE 1024-thread block per b -> 128 blocks = HALF THE CHIP idle;
//  its 268 MB of L3 re-reads ran at half-chip request rate (~50+ us).
//  Fix: back to full-chip 2048-block passes for t1/t2 (R5's proven launch skeleton),
//  but WITHOUT R5's fp16-copy write -- passes re-read the fp32 votes from L3
//  (128 MiB < 256 MiB Infinity Cache, just streamed by t0).
//   - t0   (2048 blk x 256): stream 134 MB fp32 -> per-chunk partials (~21 us HBM).
//   - t1/t2(2048 blk x 256): each block re-derives v^0 (and v^1) from the 8 KB of
//     per-b partials (redundant but trivial), then streams its 64 KB vote chunk
//     from L3 at full-chip rate. Kernel boundary IS the cross-block sync:
//     no atomics, no fences, no spins (R6-R8 lesson).
//   - finalize (16 blk x 256): reduce t=2 partials, squash, write poses+acts.
//  Full fp32 end-to-end; no per-thread state crosses a sync point (no spill mode).

#define BATCH 128
#define IC 2048
#define OC 32
#define POSE 4
#define REPS 1e-7f

#define CHUNKS 16
#define CHUNK_I (IC / CHUNKS)            // 128 input capsules per block
#define BLOCK_T 256
#define GROUPS (BLOCK_T / 32)            // 8 i-groups of 32 lanes
#define IPT (CHUNK_I / GROUPS)           // 16 i's per thread
#define ILP 4
#define STEPS (IPT / ILP)                // 4 steps of 4 quads

// partials layout: [t][b][chunk][o] float4 (3 MiB total)
#define PART_IDX(t, b, c, o) ((((size_t)(t) * BATCH + (b)) * CHUNKS + (c)) * OC + (o))

__device__ __forceinline__ float dot4(const float4 a, const float4 b) {
    return a.x*b.x + a.y*b.y + a.z*b.z + a.w*b.w;
}

// squash: v = (n2/(1+n2)) * s / sqrt(n2),  n2 = |s|^2 + eps
__device__ __forceinline__ float4 squash4(const float4 s) {
    const float n2 = s.x*s.x + s.y*s.y + s.z*s.z + s.w*s.w + REPS;
    const float f = n2 / (1.f + n2) * rsqrtf(n2);
    return make_float4(f*s.x, f*s.y, f*s.z, f*s.w);
}

// sum the 16 chunk partials for (b,o) of iteration t, apply scale, squash
__device__ __forceinline__ float4 reduce_squash(
    const float4* __restrict__ partials, int t, int b, int o, float scale)
{
    float4 acc = make_float4(0.f, 0.f, 0.f, 0.f);
    #pragma unroll
    for (int c = 0; c < CHUNKS; ++c) {
        const float4 p = partials[PART_IDX(t, b, c, o)];
        acc.x += p.x; acc.y += p.y; acc.z += p.z; acc.w += p.w;
    }
    acc.x *= scale; acc.y *= scale; acc.z *= scale; acc.w *= scale;
    return squash4(acc);
}

// block-reduce 8 group partials per o, write one chunk partial (no atomics)
__device__ __forceinline__ void block_reduce_store(
    float4 s_acc, float4* lds_s, float4* __restrict__ partials,
    int t, int b, int chunk, int g, int o)
{
    lds_s[g * 32 + o] = s_acc;
    __syncthreads();
    if (threadIdx.x < 32) {
        float4 tot = lds_s[o];
        #pragma unroll
        for (int gg = 1; gg < GROUPS; ++gg) {
            const float4 x = lds_s[gg * 32 + o];
            tot.x += x.x; tot.y += x.y; tot.z += x.z; tot.w += x.w;
        }
        partials[PART_IDX(t, b, chunk, o)] = tot;   // 512 B coalesced
    }
}

// softmax over o (32 lanes) + weighted accumulate for 4 fp32 quads.
// __shfl_xor masks 16..1 stay within each 32-lane half of the wave64,
// i.e. reduce exactly over one o-group (lane = o + 32*(g&1)).
__device__ __forceinline__ void accum4f(const float4 v0, const float4 v1,
                                        const float4 v2, const float4 v3,
                                        const float4 vh, float4& s_acc)
{
    const float l0 = dot4(v0, vh);
    const float l1 = dot4(v1, vh);
    const float l2 = dot4(v2, vh);
    const float l3 = dot4(v3, vh);
    // no max-subtraction: |logit| <~ 16 worst case (|vh01|<2) -> fp32 exp safe
    float e0 = __expf(l0), e1 = __expf(l1), e2 = __expf(l2), e3 = __expf(l3);
    float t0 = e0, t1 = e1, t2 = e2, t3 = e3;
    #pragma unroll
    for (int d = 16; d >= 1; d >>= 1) {
        t0 += __shfl_xor(t0, d);
        t1 += __shfl_xor(t1, d);
        t2 += __shfl_xor(t2, d);
        t3 += __shfl_xor(t3, d);
    }
    const float c0 = e0 * __builtin_amdgcn_rcpf(t0);
    const float c1 = e1 * __builtin_amdgcn_rcpf(t1);
    const float c2 = e2 * __builtin_amdgcn_rcpf(t2);
    const float c3 = e3 * __builtin_amdgcn_rcpf(t3);

    s_acc.x += c0*v0.x + c1*v1.x + c2*v2.x + c3*v3.x;
    s_acc.y += c0*v0.y + c1*v1.y + c2*v2.y + c3*v3.y;
    s_acc.z += c0*v0.z + c1*v1.z + c2*v2.z + c3*v3.z;
    s_acc.w += c0*v0.w + c1*v1.w + c2*v2.w + c3*v3.w;
}

// ---- t=0: streaming sum (softmax(0) = 1/32 uniform; scale applied downstream) ----
__global__ __launch_bounds__(BLOCK_T) void routing_t0(
    const float4* __restrict__ votes,
    float4* __restrict__ partials)
{
    const int b     = blockIdx.x >> 4;          // CHUNKS=16
    const int chunk = blockIdx.x & (CHUNKS - 1);
    const int o     = threadIdx.x & 31;
    const int g     = threadIdx.x >> 5;

    __shared__ float4 lds_s[GROUPS * 32];

    const float4* vb = votes + ((size_t)b * IC + (size_t)chunk * CHUNK_I) * OC;

    float4 s0 = make_float4(0.f, 0.f, 0.f, 0.f);
    #pragma unroll
    for (int s = 0; s < IPT; ++s) {
        const float4 v = vb[(size_t)(s * GROUPS + g) * OC + o];  // 1 KiB/wave
        s0.x += v.x; s0.y += v.y; s0.z += v.z; s0.w += v.w;
    }
    block_reduce_store(s0, lds_s, partials, 0, b, chunk, g, o);
}

// ---- t=1 / t=2: full-chip pass; v-history re-derived from 8 KB of partials ----
template <int T>
__global__ __launch_bounds__(BLOCK_T) void routing_pass(
    const float4* __restrict__ votes,
    float4* __restrict__ partials)
{
    const int b     = blockIdx.x >> 4;
    const int chunk = blockIdx.x & (CHUNKS - 1);
    const int o     = threadIdx.x & 31;
    const int g     = threadIdx.x >> 5;

    __shared__ float4 lds_s[GROUPS * 32];
    __shared__ float4 vh_s[32];

    if (threadIdx.x < 32) {
        float4 vh = reduce_squash(partials, 0, b, o, 1.f / 32.f);   // v^0
        if (T == 2) {
            const float4 v1 = reduce_squash(partials, 1, b, o, 1.f); // v^1
            // t=2 logit = dot(v, v0) + dot(v, v1) == dot(v, v0+v1)
            vh.x += v1.x; vh.y += v1.y; vh.z += v1.z; vh.w += v1.w;
        }
        vh_s[o] = vh;
    }
    __syncthreads();
    const float4 vh = vh_s[o];

    const float4* vb = votes + ((size_t)b * IC + (size_t)chunk * CHUNK_I) * OC;

    float4 s_acc = make_float4(0.f, 0.f, 0.f, 0.f);
    #pragma unroll
    for (int st = 0; st < STEPS; ++st) {
        const int base = st * (ILP * GROUPS) + g;
        const float4 v0 = vb[(size_t)(base + 0 * GROUPS) * OC + o];  // L3-resident
        const float4 v1 = vb[(size_t)(base + 1 * GROUPS) * OC + o];
        const float4 v2 = vb[(size_t)(base + 2 * GROUPS) * OC + o];
        const float4 v3 = vb[(size_t)(base + 3 * GROUPS) * OC + o];
        accum4f(v0, v1, v2, v3, vh, s_acc);
    }
    block_reduce_store(s_acc, lds_s, partials, T, b, chunk, g, o);
}

// ---- finalize: reduce t=2 partials, squash, write poses + activations ----
__global__ __launch_bounds__(256) void routing_finalize(
    const float4* __restrict__ partials,
    float* __restrict__ out)             // poses [B,O,P] then acts [B,O,1]
{
    const int idx = blockIdx.x * blockDim.x + threadIdx.x;  // one (b,o) per thread
    if (idx >= BATCH * OC) return;
    const int b = idx >> 5, o = idx & 31;
    const float4 v = reduce_squash(partials, 2, b, o, 1.f);
    ((float4*)out)[idx] = v;                                       // poses_out
    const float a = sqrtf(v.x*v.x + v.y*v.y + v.z*v.z + v.w*v.w + REPS);
    out[BATCH * OC * POSE + idx] = a;                              // activations
}

extern "C" void kernel_launch(void* const* d_in, const int* in_sizes, int n_in,
                              void* d_out, int out_size, void* d_ws, size_t ws_size,
                              hipStream_t stream) {
    const float4* votes = (const float4*)d_in[0];
    // d_in[1] (activations_in) unused by the reference.

    // ws layout: partials [3][B][CHUNKS][O] float4 (3 MiB)
    float4* partials = (float4*)d_ws;

    routing_t0<<<BATCH * CHUNKS, BLOCK_T, 0, stream>>>(votes, partials);
    routing_pass<1><<<BATCH * CHUNKS, BLOCK_T, 0, stream>>>(votes, partials);
    routing_pass<2><<<BATCH * CHUNKS, BLOCK_T, 0, stream>>>(votes, partials);
    routing_finalize<<<(BATCH * OC + 255) / 256, 256, 0, stream>>>(
        partials, (float*)d_out);
}